// Round 4
// baseline (399.729 us; speedup 1.0000x reference)
//
#include <hip/hip_runtime.h>
#include <hip/hip_bf16.h>

// Binarized-weight 3x3 conv as implicit GEMM:
//   out[n,o,h,w] = sum_{c,kh,kw} sign(W[o,c,kh,kw]) * x[n,c,h+kh-1,w+kw-1]
// GEMM: D[o][p] = sum_k Wmat[o][k] * B[k][p],  k = (kh*3+kw)*128 + c.
// R6 = R2's proven 128o x 256px / 4-wave / 2-blocks-per-CU shape (R4/R5
// post-mortem: 8-wave variants spilled past the 256-reg cap -> 300 MB of
// scratch round-trips; R3/R2's 104 arch + 128 acc fits) + counted-vmcnt
// pipeline grafted with minimal extra liveness:
//  - A dbuf 2x16 KB, B single 33 KB (65 KB LDS, 2 blocks/CU kept).
//  - 18 phases; per phase: vmcnt(4); barrier; kf0 reads+MFMA; kf1 reads;
//    lgkmcnt(0); barrier2; issue A(p+2) [+B(s+1) at kw2, B first]; kf1
//    MFMA. Steady-state outstanding at entry is always 4 newest A-loads
//    -> vmcnt(4) everywhere (vmcnt(0) only at p=17). Each stage drains
//    two phases (~2.5K cyc of MFMA) after issue.

typedef short bf16x8 __attribute__((ext_vector_type(8)));
typedef float f32x4 __attribute__((ext_vector_type(4)));

#define XT_ELEMS (32 * 66 * 66 * 128)
#define XT_BYTES (XT_ELEMS * 2)

#define VMW4 asm volatile("s_waitcnt vmcnt(4)" ::: "memory")
#define VMW0 asm volatile("s_waitcnt vmcnt(0)" ::: "memory")
#define LGKM0 asm volatile("s_waitcnt lgkmcnt(0)" ::: "memory")

__device__ __forceinline__ void glds16(const void* g, const void* l) {
    __builtin_amdgcn_global_load_lds(
        (const __attribute__((address_space(1))) void*)g,
        (__attribute__((address_space(3))) void*)l, 16, 0, 0);
}

// weight OIHW fp32 -> Wmat[o][j][c] = sign(w[o][c][j]) as bf16, j = kh*3+kw
__global__ void prep_w_kernel(const float* __restrict__ w,
                              __hip_bfloat16* __restrict__ wm) {
    int tid = blockIdx.x * 256 + threadIdx.x;   // 294912 total, exact grid
    int o = tid / 1152;
    int r = tid - o * 1152;
    int j = r >> 7;
    int c = r & 127;
    float v = w[o * 1152 + c * 9 + j];
    float s = (v > 0.f) ? 1.f : ((v < 0.f) ? -1.f : 0.f);
    wm[tid] = __float2bfloat16(s);
}

// x NCHW fp32 -> x_t[n][h+1][w+1][c] bf16 (66x66 spatial, zero halo).
__global__ void transpose_x_kernel(const float* __restrict__ x,
                                   __hip_bfloat16* __restrict__ xt) {
    __shared__ short tl[64 * 130];   // stride 130: +65 banks/row -> 2-way max
    const int t = threadIdx.x;
    const int n = blockIdx.x >> 6;
    const int h = blockIdx.x & 63;
    const float* xp = x + (size_t)n * 524288 + h * 64;
    for (int i = t; i < 8192; i += 256) {
        int w = i & 63, c = i >> 6;
        tl[w * 130 + c] = (short)__bfloat16_as_ushort(__float2bfloat16(xp[c * 4096 + w]));
    }
    uint* xtn = (uint*)(xt + (size_t)n * 66 * 66 * 128);
    {
        int row = h + 1;
        if (t < 64)       xtn[(row * 66 + 0) * 64 + t] = 0u;
        else if (t < 128) xtn[(row * 66 + 65) * 64 + (t - 64)] = 0u;
    }
    if (h == 0)  for (int i = t; i < 66 * 64; i += 256) xtn[i] = 0u;
    if (h == 63) for (int i = t; i < 66 * 64; i += 256) xtn[65 * 66 * 64 + i] = 0u;
    __syncthreads();
    uint* xo = (uint*)(xt + ((size_t)(n * 66 + h + 1) * 66 + 1) * 128);
    for (int i = t; i < 4096; i += 256) {
        int c2 = i & 63;
        int w = i >> 6;
        xo[w * 64 + c2] = *(const uint*)(tl + w * 130 + c2 * 2);
    }
}

// Block: 128 o x 256 px (4 out rows of one n). 4 waves, each 64o x 128px.
// LDS: As dbuf 2x[128 o][64 c] (16 KB each), Bw single [4x66 cells][64 c]
// (33 KB). 16B segs XOR-swizzled by (row&7)/(cell&7): ds_read_b128 2-way
// max (R2-measured 0 conflicts).
__global__ __launch_bounds__(256, 2) void gemm_kernel(
    const __hip_bfloat16* __restrict__ xt,
    const __hip_bfloat16* __restrict__ wm,
    float* __restrict__ out) {
    __shared__ short As[2][128 * 64];   // 2 x 16384 B
    __shared__ short Bw[264 * 64];      // 33792 B

    const int t = threadIdx.x;
    const int lane = t & 63;
    const int wv = t >> 6;              // 0..3
    const int l15 = lane & 15;
    const int quad = lane >> 4;
    const int srow = lane >> 3;
    const int sseg = lane & 7;

    const int bid = blockIdx.x;                       // 0..511
    const int px_blk = (bid & 7) * 64 + (bid >> 3);   // XCD-chunked (512%8==0)
    const int o_blk = blockIdx.y;                     // 0..1
    const int n = px_blk >> 4;
    const int h0 = (px_blk & 15) * 4;

    const int wo = (wv & 1) * 64;       // wave origin in o
    const int wp = (wv >> 1) * 128;     // wave origin in px
    const int wpr = wp >> 6;            // wave px-row origin (0 or 2)

    const short* wmS = (const short*)wm + (o_blk * 128) * 1152;
    const short* xtB = (const short*)xt + ((size_t)(n * 66 + h0) * 66) * 128;

    f32x4 acc[4][8] = {};   // [o frag][px frag]

    // stage A(cc,j) into As[buf]: 128 o x 64 c, 4 issues/wave (16 total)
    auto stageA = [&](int buf, int cc, int j) {
#pragma unroll
        for (int i = 0; i < 4; ++i) {
            int r0 = wv * 32 + i * 8;
            int r = r0 + srow;
            int segl = sseg ^ (r & 7);
            glds16(wmS + r * 1152 + j * 128 + cc + segl * 8,
                   &As[buf][r0 * 64]);
        }
    };
    // stage B(cc,kh): rows (h0+kh..h0+kh+3) x 66 cols x 64 c = 33 seg-blocks;
    // 9 issues/wave uniform (waves 1-3 duplicate block 32: same src+dest,
    // benign; keeps per-wave vmcnt counts identical).
    auto stageB = [&](int cc, int kh) {
        const short* src = xtB + kh * (66 * 128) + cc;
#pragma unroll
        for (int i = 0; i < 9; ++i) {
            int bidx = i * 4 + wv;
            if (bidx > 32) bidx = 32;
            int l = bidx * 64 + lane;
            int cell = l >> 3;
            int q = l & 7;
            glds16(src + cell * 128 + ((q ^ (cell & 7)) * 8),
                   &Bw[bidx * 512]);
        }
    };

    // prologue: B(s0), A0->buf0, A1->buf1 (17 outstanding/wave)
    stageB(0, 0);
    stageA(0, 0, 0);
    stageA(1, 0, 1);

    int ab = 0;
    for (int s = 0; s < 6; ++s) {
        const int cc = (s >= 3) ? 64 : 0;
        const int kh = s % 3;
#pragma unroll
        for (int kw = 0; kw < 3; ++kw) {
            const int p = s * 3 + kw;
            // entry drain: completes A(p) [+B(s) at kw0], leaves newest 4
            if (p == 17) { VMW0; } else { VMW4; }
            __builtin_amdgcn_s_barrier();
            // ---- kf = 0: reads + MFMA
            {
                bf16x8 a[4], b[8];
#pragma unroll
                for (int i = 0; i < 4; ++i) {
                    int o = wo + i * 16 + l15;
                    a[i] = *(const bf16x8*)(&As[ab][o * 64 + ((quad ^ (o & 7)) * 8)]);
                }
#pragma unroll
                for (int i = 0; i < 8; ++i) {
                    int cell = (wpr + (i >> 2)) * 66 + (i & 3) * 16 + l15 + kw;
                    int seg = quad ^ (cell & 7);
                    b[i] = *(const bf16x8*)(&Bw[cell * 64 + seg * 8]);
                }
                __builtin_amdgcn_s_setprio(1);
#pragma unroll
                for (int i = 0; i < 4; ++i)
#pragma unroll
                    for (int jj = 0; jj < 8; ++jj)
                        acc[i][jj] = __builtin_amdgcn_mfma_f32_16x16x32_bf16(
                            a[i], b[jj], acc[i][jj], 0, 0, 0);
                __builtin_amdgcn_s_setprio(0);
            }
            // ---- kf = 1: reads, then barrier2 + issues, then MFMA
            {
                bf16x8 a[4], b[8];
#pragma unroll
                for (int i = 0; i < 4; ++i) {
                    int o = wo + i * 16 + l15;
                    a[i] = *(const bf16x8*)(&As[ab][o * 64 + (((4 + quad) ^ (o & 7)) * 8)]);
                }
#pragma unroll
                for (int i = 0; i < 8; ++i) {
                    int cell = (wpr + (i >> 2)) * 66 + (i & 3) * 16 + l15 + kw;
                    int seg = (4 + quad) ^ (cell & 7);
                    b[i] = *(const bf16x8*)(&Bw[cell * 64 + seg * 8]);
                }
                LGKM0;                              // all my LDS reads landed
                __builtin_amdgcn_s_barrier();       // all waves done reading
                // issue next stages (B first, then A: newest 4 must be A)
                if (kw == 2 && s < 5)
                    stageB((s + 1) >= 3 ? 64 : 0, (s + 1) % 3);
                if (p <= 15) {
                    int pn = p + 2, sn = pn / 3, kwn = pn % 3;
                    stageA(ab, (sn >= 3) ? 64 : 0, (sn % 3) * 3 + kwn);
                }
                __builtin_amdgcn_s_setprio(1);
#pragma unroll
                for (int i = 0; i < 4; ++i)
#pragma unroll
                    for (int jj = 0; jj < 8; ++jj)
                        acc[i][jj] = __builtin_amdgcn_mfma_f32_16x16x32_bf16(
                            a[i], b[jj], acc[i][jj], 0, 0, 0);
                __builtin_amdgcn_s_setprio(0);
            }
            ab ^= 1;
        }
    }

    // Epilogue: C/D layout col=lane&15 (px), row=quad*4+reg (o)
    const int Pbase = px_blk * 256 + wp;
#pragma unroll
    for (int i = 0; i < 4; ++i) {
#pragma unroll
        for (int jj = 0; jj < 8; ++jj) {
            const int P = Pbase + jj * 16 + l15;
            const int hw = P & 4095;
            float* op = out + (size_t)n * 1048576 + hw;
#pragma unroll
            for (int r = 0; r < 4; ++r) {
                const int o = o_blk * 128 + wo + i * 16 + quad * 4 + r;
                op[(size_t)o * 4096] = acc[i][jj][r];
            }
        }
    }
}

extern "C" void kernel_launch(void* const* d_in, const int* in_sizes, int n_in,
                              void* d_out, int out_size, void* d_ws, size_t ws_size,
                              hipStream_t stream) {
    const float* x = (const float*)d_in[0];
    const float* w = (const float*)d_in[1];
    float* out = (float*)d_out;
    __hip_bfloat16* xt = (__hip_bfloat16*)d_ws;
    __hip_bfloat16* wm = (__hip_bfloat16*)((char*)d_ws + XT_BYTES);

    prep_w_kernel<<<1152, 256, 0, stream>>>(w, wm);
    transpose_x_kernel<<<2048, 256, 0, stream>>>(x, xt);
    gemm_kernel<<<dim3(512, 2), 256, 0, stream>>>(xt, wm, out);
}

// Round 6
// 278.319 us; speedup vs baseline: 1.4362x; 1.4362x over previous
//
#include <hip/hip_runtime.h>
#include <hip/hip_bf16.h>

// Binarized-weight 3x3 conv as implicit GEMM:
//   out[n,o,h,w] = sum_{c,kh,kw} sign(W[o,c,kh,kw]) * x[n,c,h+kh-1,w+kw-1]
// GEMM: D[o][p] = sum_k Wmat[o][k] * B[k][p],  k = (kh*3+kw)*128 + c.
// R8 = R7 with the missing cc64-row3 stage added (R7 failed refcheck:
// phys row 1 was never restaged for cc64 -> windows s>=3 read stale cc0
// data; absmax 117 matched the expected magnitude of that exact bug).
// Structure: R2's proven 128o x 256px / 4-wave / 2-blocks-per-CU shape,
//  - A fragments loaded straight into registers from a fragment-native
//    weight layout wm2[j][c8][o][8c] (one coalesced 16B load per frag;
//    wm2 = 576 KB, L2-resident). A-LDS/A-barriers gone. A-readiness is a
//    REGISTER dep -> compiler emits exact counted vmcnt, which (FIFO)
//    also drains all older B-glds without touching newer ones.
//  - B: 8-row circular LDS buffer (67.6 KB, 2 blocks/CU kept). Only NEW
//    rows staged (12 row-stages vs R2's 24), >=1 kw-phase ahead, always
//    into rows outside every live window. Barriers at s-entries only.
//  - R5/R6 lesson: no hand-held fragments across asm fences -> register
//    peak ~100 arch + 128 acc, below the 256 cap (spill was the killer).

typedef short bf16x8 __attribute__((ext_vector_type(8)));
typedef float f32x4 __attribute__((ext_vector_type(4)));

#define XT_ELEMS (32 * 66 * 66 * 128)
#define XT_BYTES (XT_ELEMS * 2)

__device__ __forceinline__ void glds16(const void* g, const void* l) {
    __builtin_amdgcn_global_load_lds(
        (const __attribute__((address_space(1))) void*)g,
        (__attribute__((address_space(3))) void*)l, 16, 0, 0);
}

// weight OIHW fp32 -> wm2[((j*16 + c8)*256 + o)*8 + e] = sign(w[o][c8*8+e][j])
// (fragment-native: lane fragment (o, c8) = 16 contiguous bytes)
__global__ void prep_w_kernel(const float* __restrict__ w,
                              __hip_bfloat16* __restrict__ wm) {
    int tid = blockIdx.x * 256 + threadIdx.x;   // 294912 total, exact grid
    int e = tid & 7;
    int o = (tid >> 3) & 255;
    int c8 = (tid >> 11) & 15;
    int j = tid >> 15;                          // 0..8
    float v = w[o * 1152 + (c8 * 8 + e) * 9 + j];
    float s = (v > 0.f) ? 1.f : ((v < 0.f) ? -1.f : 0.f);
    wm[tid] = __float2bfloat16(s);
}

// x NCHW fp32 -> x_t[n][h+1][w+1][c] bf16 (66x66 spatial, zero halo).
__global__ void transpose_x_kernel(const float* __restrict__ x,
                                   __hip_bfloat16* __restrict__ xt) {
    __shared__ short tl[64 * 130];   // stride 130: +65 banks/row -> 2-way max
    const int t = threadIdx.x;
    const int n = blockIdx.x >> 6;
    const int h = blockIdx.x & 63;
    const float* xp = x + (size_t)n * 524288 + h * 64;
    for (int i = t; i < 8192; i += 256) {
        int w = i & 63, c = i >> 6;
        tl[w * 130 + c] = (short)__bfloat16_as_ushort(__float2bfloat16(xp[c * 4096 + w]));
    }
    uint* xtn = (uint*)(xt + (size_t)n * 66 * 66 * 128);
    {
        int row = h + 1;
        if (t < 64)       xtn[(row * 66 + 0) * 64 + t] = 0u;
        else if (t < 128) xtn[(row * 66 + 65) * 64 + (t - 64)] = 0u;
    }
    if (h == 0)  for (int i = t; i < 66 * 64; i += 256) xtn[i] = 0u;
    if (h == 63) for (int i = t; i < 66 * 64; i += 256) xtn[65 * 66 * 64 + i] = 0u;
    __syncthreads();
    uint* xo = (uint*)(xt + ((size_t)(n * 66 + h + 1) * 66 + 1) * 128);
    for (int i = t; i < 4096; i += 256) {
        int c2 = i & 63;
        int w = i >> 6;
        xo[w * 64 + c2] = *(const uint*)(tl + w * 130 + c2 * 2);
    }
}

// Block: 128 o x 256 px (4 out rows of one n). 4 waves, each 64o x 128px.
// Bw: 8 phys rows x 66 cols x 64 c = 67584 B. Row content: cc0 rows 0-5
// -> phys 0-5; cc64 row r -> phys (r+6)&7 = 6,7,0,1,2,3. Window(s): phys
// (base[s]+widx)&7, base = {0,1,2,6,7,0}. Stage schedule (all targets
// outside every live window; each drained by next kw's A-register wait):
//   s0kw0: p4<-r4,cc0   s1kw0: p5<-r5,cc0   s1kw1: p6<-r0,cc64
//   s1kw2: p7<-r1,cc64  s2kw0: p0<-r2,cc64  s2kw1: p1<-r3,cc64  [R8 FIX]
//   s3kw0: p2<-r4,cc64  s4kw0: p3<-r5,cc64
// Col-swizzle: seg (col,q) stored at col*8 + (q^(col&7)) -> ds_read_b128
// 2-way max (free).
__global__ __launch_bounds__(256, 2) void gemm_kernel(
    const __hip_bfloat16* __restrict__ xt,
    const __hip_bfloat16* __restrict__ wm,
    float* __restrict__ out) {
    __shared__ short Bw[8 * 4224];   // 67584 B

    const int t = threadIdx.x;
    const int lane = t & 63;
    const int wv = t >> 6;              // 0..3
    const int l15 = lane & 15;
    const int quad = lane >> 4;

    const int bid = blockIdx.x;                       // 0..511
    const int px_blk = (bid & 7) * 64 + (bid >> 3);   // XCD-chunked (512%8==0)
    const int o_blk = blockIdx.y;                     // 0..1
    const int n = px_blk >> 4;
    const int h0 = (px_blk & 15) * 4;

    const int wo = (wv & 1) * 64;       // wave origin in o
    const int wp = (wv >> 1) * 128;     // wave origin in px
    const int wpr = wp >> 6;            // wave px-row origin (0 or 2)

    const short* xtB = (const short*)xt + ((size_t)(n * 66 + h0) * 66) * 128;
    // lane A base: o = o_blk*128 + wo + l15 (+i*16), c8 = quad (+ccA+kf*4)
    const short* aL = (const short*)wm +
        (size_t)(o_blk * 128 + wo + l15) * 8 + quad * 2048;

    f32x4 acc[4][8] = {};   // [o frag][px frag]

    // stage one B row (rel spatial row r, channel off ccv) into phys pr.
    // 528 segs: wave w covers [w*128, w*128+127] (2 glds); wave0 adds
    // [464,527] (dup segs 464-511 rewrite same data -> benign).
    auto stageRow = [&](int pr, int r, int ccv) {
        const short* src = xtB + r * (66 * 128) + ccv;
        short* dst = (short*)&Bw[pr * 4224];
        const int s0 = wv * 128;
        {
            int l = s0 + lane; int col = l >> 3, q = l & 7;
            glds16(src + col * 128 + ((q ^ (col & 7)) * 8), dst + s0 * 8);
        }
        {
            int l = s0 + 64 + lane; int col = l >> 3, q = l & 7;
            glds16(src + col * 128 + ((q ^ (col & 7)) * 8), dst + (s0 + 64) * 8);
        }
        if (wv == 0) {
            int l = 464 + lane; int col = l >> 3, q = l & 7;
            glds16(src + col * 128 + ((q ^ (col & 7)) * 8), dst + 464 * 8);
        }
    };

    // prologue: W0 = rows 0-3 (cc0) -> phys 0-3
    stageRow(0, 0, 0);
    stageRow(1, 1, 0);
    stageRow(2, 2, 0);
    stageRow(3, 3, 0);

    const int baseT[6] = {0, 1, 2, 6, 7, 0};

#pragma unroll
    for (int s = 0; s < 6; ++s) {
        // s-entry: incoming rows' glds were drained by compiler A-waits
        // >=1 kw-phase ago; barrier makes them visible across waves.
        if (s == 0) { asm volatile("s_waitcnt vmcnt(0)" ::: "memory"); }
        else        { asm volatile("s_waitcnt vmcnt(3)" ::: "memory"); }
        __builtin_amdgcn_s_barrier();
        const int kh = (s >= 3) ? (s - 3) : s;
        const int base = baseT[s];
        const int ccA = (s >= 3) ? 8 : 0;      // c8 offset for cc64
#pragma unroll
        for (int kw = 0; kw < 3; ++kw) {
            const int j = kh * 3 + kw;
            // A fragment loads FIRST (register dep -> compiler counted
            // vmcnt; everything issued after stays in flight)
            const short* ap = aL + j * 32768 + ccA * 2048;
            bf16x8 a0[4], a1[4];
#pragma unroll
            for (int i = 0; i < 4; ++i)
                a0[i] = *(const bf16x8*)(ap + i * 128);
#pragma unroll
            for (int i = 0; i < 4; ++i)
                a1[i] = *(const bf16x8*)(ap + 8192 + i * 128);
            // B row stages (targets never in a live window; see table)
            if (kw == 0) {
                if (s == 0)      stageRow(4, 4, 0);
                else if (s == 1) stageRow(5, 5, 0);
                else if (s == 2) stageRow(0, 2, 64);
                else if (s == 3) stageRow(2, 4, 64);
                else if (s == 4) stageRow(3, 5, 64);
            } else if (kw == 1) {
                if (s == 1)      stageRow(6, 0, 64);
                else if (s == 2) stageRow(1, 3, 64);   // R8 FIX: cc64 row3
            } else { // kw == 2
                if (s == 1)      stageRow(7, 1, 64);
            }
            // compute
#pragma unroll
            for (int kf = 0; kf < 2; ++kf) {
                bf16x8 b[8];
#pragma unroll
                for (int i = 0; i < 8; ++i) {
                    int pr = (base + wpr + (i >> 2)) & 7;
                    int col = (i & 3) * 16 + l15 + kw;
                    int k = kf * 4 + quad;
                    b[i] = *(const bf16x8*)(
                        &Bw[pr * 4224 + col * 64 + ((k ^ (col & 7)) * 8)]);
                }
                __builtin_amdgcn_s_setprio(1);
#pragma unroll
                for (int i = 0; i < 4; ++i)
#pragma unroll
                    for (int jj = 0; jj < 8; ++jj)
                        acc[i][jj] = __builtin_amdgcn_mfma_f32_16x16x32_bf16(
                            kf ? a1[i] : a0[i], b[jj], acc[i][jj], 0, 0, 0);
                __builtin_amdgcn_s_setprio(0);
            }
            // pin VMEM to its phase (stop unroller hoisting loads of
            // later phases -> R5/R6's spill); ALU/MFMA/DS may cross.
            __builtin_amdgcn_sched_barrier(0x38F);
        }
    }

    // Epilogue: C/D layout col=lane&15 (px), row=quad*4+reg (o)
    const int Pbase = px_blk * 256 + wp;
#pragma unroll
    for (int i = 0; i < 4; ++i) {
#pragma unroll
        for (int jj = 0; jj < 8; ++jj) {
            const int P = Pbase + jj * 16 + l15;
            const int hw = P & 4095;
            float* op = out + (size_t)n * 1048576 + hw;
#pragma unroll
            for (int r = 0; r < 4; ++r) {
                const int o = o_blk * 128 + wo + i * 16 + quad * 4 + r;
                op[(size_t)o * 4096] = acc[i][jj][r];
            }
        }
    }
}

extern "C" void kernel_launch(void* const* d_in, const int* in_sizes, int n_in,
                              void* d_out, int out_size, void* d_ws, size_t ws_size,
                              hipStream_t stream) {
    const float* x = (const float*)d_in[0];
    const float* w = (const float*)d_in[1];
    float* out = (float*)d_out;
    __hip_bfloat16* xt = (__hip_bfloat16*)d_ws;
    __hip_bfloat16* wm = (__hip_bfloat16*)((char*)d_ws + XT_BYTES);

    prep_w_kernel<<<1152, 256, 0, stream>>>(w, wm);
    transpose_x_kernel<<<2048, 256, 0, stream>>>(x, xt);
    gemm_kernel<<<dim3(512, 2), 256, 0, stream>>>(xt, wm, out);
}

// Round 7
// 271.824 us; speedup vs baseline: 1.4705x; 1.0239x over previous
//
#include <hip/hip_runtime.h>
#include <hip/hip_bf16.h>

// Binarized-weight 3x3 conv as implicit GEMM:
//   out[n,o,h,w] = sum_{c,kh,kw} sign(W[o,c,kh,kw]) * x[n,c,h+kh-1,w+kw-1]
// GEMM: D[o][p] = sum_k Wmat[o][k] * B[k][p],  k = (kh*3+kw)*128 + c.
// R9 = R8 (passing) with the spill removed:
//  - sched_barrier(0) at each kw-phase end (R8's 0x38F let DS/MFMA cross
//    phases -> b-fragment liveness stretched a full phase -> spill; VGPR
//    pinned at 128 = 256-cap minus acc, WRITE_SIZE showed +74 MB scratch).
//  - stageRow per-lane swizzled offsets hoisted to loop-invariants.
// Structure (unchanged from R8): R2's 128o x 256px / 4-wave / 2-blk-per-CU,
// A fragments direct from fragment-native wm2[j][c8][o][8c] (L2-resident,
// register dep -> compiler-counted vmcnt leaves newer B-glds in flight),
// B in an 8-row circular LDS buffer (67.6 KB), rows staged >=1 kw-phase
// ahead into rows outside every live window, barriers at s-entries only.

typedef short bf16x8 __attribute__((ext_vector_type(8)));
typedef float f32x4 __attribute__((ext_vector_type(4)));

#define XT_ELEMS (32 * 66 * 66 * 128)
#define XT_BYTES (XT_ELEMS * 2)

__device__ __forceinline__ void glds16(const void* g, const void* l) {
    __builtin_amdgcn_global_load_lds(
        (const __attribute__((address_space(1))) void*)g,
        (__attribute__((address_space(3))) void*)l, 16, 0, 0);
}

// weight OIHW fp32 -> wm2[((j*16 + c8)*256 + o)*8 + e] = sign(w[o][c8*8+e][j])
// (fragment-native: lane fragment (o, c8) = 16 contiguous bytes)
__global__ void prep_w_kernel(const float* __restrict__ w,
                              __hip_bfloat16* __restrict__ wm) {
    int tid = blockIdx.x * 256 + threadIdx.x;   // 294912 total, exact grid
    int e = tid & 7;
    int o = (tid >> 3) & 255;
    int c8 = (tid >> 11) & 15;
    int j = tid >> 15;                          // 0..8
    float v = w[o * 1152 + (c8 * 8 + e) * 9 + j];
    float s = (v > 0.f) ? 1.f : ((v < 0.f) ? -1.f : 0.f);
    wm[tid] = __float2bfloat16(s);
}

// x NCHW fp32 -> x_t[n][h+1][w+1][c] bf16 (66x66 spatial, zero halo).
__global__ void transpose_x_kernel(const float* __restrict__ x,
                                   __hip_bfloat16* __restrict__ xt) {
    __shared__ short tl[64 * 130];   // stride 130: +65 banks/row -> 2-way max
    const int t = threadIdx.x;
    const int n = blockIdx.x >> 6;
    const int h = blockIdx.x & 63;
    const float* xp = x + (size_t)n * 524288 + h * 64;
    for (int i = t; i < 8192; i += 256) {
        int w = i & 63, c = i >> 6;
        tl[w * 130 + c] = (short)__bfloat16_as_ushort(__float2bfloat16(xp[c * 4096 + w]));
    }
    uint* xtn = (uint*)(xt + (size_t)n * 66 * 66 * 128);
    {
        int row = h + 1;
        if (t < 64)       xtn[(row * 66 + 0) * 64 + t] = 0u;
        else if (t < 128) xtn[(row * 66 + 65) * 64 + (t - 64)] = 0u;
    }
    if (h == 0)  for (int i = t; i < 66 * 64; i += 256) xtn[i] = 0u;
    if (h == 63) for (int i = t; i < 66 * 64; i += 256) xtn[65 * 66 * 64 + i] = 0u;
    __syncthreads();
    uint* xo = (uint*)(xt + ((size_t)(n * 66 + h + 1) * 66 + 1) * 128);
    for (int i = t; i < 4096; i += 256) {
        int c2 = i & 63;
        int w = i >> 6;
        xo[w * 64 + c2] = *(const uint*)(tl + w * 130 + c2 * 2);
    }
}

// Block: 128 o x 256 px (4 out rows of one n). 4 waves, each 64o x 128px.
// Bw: 8 phys rows x 66 cols x 64 c = 67584 B. cc0 rows 0-5 -> phys 0-5;
// cc64 row r -> phys (r+6)&7. Window(s): phys (base[s]+widx)&7,
// base = {0,1,2,6,7,0}. Stage schedule (targets outside every live
// window; each drained by next kw's A-register vmcnt wait):
//   s0kw0: p4<-r4,cc0   s1kw0: p5<-r5,cc0   s1kw1: p6<-r0,cc64
//   s1kw2: p7<-r1,cc64  s2kw0: p0<-r2,cc64  s2kw1: p1<-r3,cc64
//   s3kw0: p2<-r4,cc64  s4kw0: p3<-r5,cc64
// Col-swizzle: seg (col,q) at col*8 + (q^(col&7)) -> ds_read_b128 2-way max.
__global__ __launch_bounds__(256, 2) void gemm_kernel(
    const __hip_bfloat16* __restrict__ xt,
    const __hip_bfloat16* __restrict__ wm,
    float* __restrict__ out) {
    __shared__ short Bw[8 * 4224];   // 67584 B

    const int t = threadIdx.x;
    const int lane = t & 63;
    const int wv = t >> 6;              // 0..3
    const int l15 = lane & 15;
    const int quad = lane >> 4;

    const int bid = blockIdx.x;                       // 0..511
    const int px_blk = (bid & 7) * 64 + (bid >> 3);   // XCD-chunked (512%8==0)
    const int o_blk = blockIdx.y;                     // 0..1
    const int n = px_blk >> 4;
    const int h0 = (px_blk & 15) * 4;

    const int wo = (wv & 1) * 64;       // wave origin in o
    const int wp = (wv >> 1) * 128;     // wave origin in px
    const int wpr = wp >> 6;            // wave px-row origin (0 or 2)

    const short* xtB = (const short*)xt + ((size_t)(n * 66 + h0) * 66) * 128;
    // lane A base: o = o_blk*128 + wo + l15 (+i*16), c8 = quad (+ccA+kf*4)
    const short* aL = (const short*)wm +
        (size_t)(o_blk * 128 + wo + l15) * 8 + quad * 2048;

    // loop-invariant per-lane stage offsets (R9: hoisted out of stageRow)
    const int l0 = wv * 128 + lane, l1 = l0 + 64, l2 = 464 + lane;
    const int gs0 = (l0 >> 3) * 128 + (((l0 & 7) ^ ((l0 >> 3) & 7)) * 8);
    const int gs1 = (l1 >> 3) * 128 + (((l1 & 7) ^ ((l1 >> 3) & 7)) * 8);
    const int gs2 = (l2 >> 3) * 128 + (((l2 & 7) ^ ((l2 >> 3) & 7)) * 8);
    const int gd0 = (wv * 128) * 8;
    const int gd1 = (wv * 128 + 64) * 8;
    const int gd2 = 464 * 8;

    f32x4 acc[4][8] = {};   // [o frag][px frag]

    // stage one B row (rel spatial row r, channel off ccv) into phys pr.
    // 528 segs: wave w covers [w*128, w*128+127]; wave0 adds [464,527]
    // (dup segs 464-511 rewrite identical data -> benign).
    auto stageRow = [&](int pr, int r, int ccv) {
        const short* src = xtB + r * (66 * 128) + ccv;
        short* dst = (short*)&Bw[pr * 4224];
        glds16(src + gs0, dst + gd0);
        glds16(src + gs1, dst + gd1);
        if (wv == 0) glds16(src + gs2, dst + gd2);
    };

    // prologue: W0 = rows 0-3 (cc0) -> phys 0-3
    stageRow(0, 0, 0);
    stageRow(1, 1, 0);
    stageRow(2, 2, 0);
    stageRow(3, 3, 0);

    const int baseT[6] = {0, 1, 2, 6, 7, 0};

#pragma unroll
    for (int s = 0; s < 6; ++s) {
        // s-entry: incoming rows' glds were drained by compiler A-waits
        // >=1 kw-phase ago; barrier makes them visible across waves.
        if (s == 0) { asm volatile("s_waitcnt vmcnt(0)" ::: "memory"); }
        else        { asm volatile("s_waitcnt vmcnt(3)" ::: "memory"); }
        __builtin_amdgcn_s_barrier();
        const int kh = (s >= 3) ? (s - 3) : s;
        const int base = baseT[s];
        const int ccA = (s >= 3) ? 8 : 0;      // c8 offset for cc64
#pragma unroll
        for (int kw = 0; kw < 3; ++kw) {
            const int j = kh * 3 + kw;
            // A fragment loads FIRST (register dep -> compiler counted
            // vmcnt; everything issued after stays in flight)
            const short* ap = aL + j * 32768 + ccA * 2048;
            bf16x8 a0[4], a1[4];
#pragma unroll
            for (int i = 0; i < 4; ++i)
                a0[i] = *(const bf16x8*)(ap + i * 128);
#pragma unroll
            for (int i = 0; i < 4; ++i)
                a1[i] = *(const bf16x8*)(ap + 8192 + i * 128);
            // B row stages (targets never in a live window; see table)
            if (kw == 0) {
                if (s == 0)      stageRow(4, 4, 0);
                else if (s == 1) stageRow(5, 5, 0);
                else if (s == 2) stageRow(0, 2, 64);
                else if (s == 3) stageRow(2, 4, 64);
                else if (s == 4) stageRow(3, 5, 64);
            } else if (kw == 1) {
                if (s == 1)      stageRow(6, 0, 64);
                else if (s == 2) stageRow(1, 3, 64);
            } else { // kw == 2
                if (s == 1)      stageRow(7, 1, 64);
            }
            // compute
#pragma unroll
            for (int kf = 0; kf < 2; ++kf) {
                bf16x8 b[8];
#pragma unroll
                for (int i = 0; i < 8; ++i) {
                    int pr = (base + wpr + (i >> 2)) & 7;
                    int col = (i & 3) * 16 + l15 + kw;
                    int k = kf * 4 + quad;
                    b[i] = *(const bf16x8*)(
                        &Bw[pr * 4224 + col * 64 + ((k ^ (col & 7)) * 8)]);
                }
                __builtin_amdgcn_s_setprio(1);
#pragma unroll
                for (int i = 0; i < 4; ++i)
#pragma unroll
                    for (int jj = 0; jj < 8; ++jj)
                        acc[i][jj] = __builtin_amdgcn_mfma_f32_16x16x32_bf16(
                            kf ? a1[i] : a0[i], b[jj], acc[i][jj], 0, 0, 0);
                __builtin_amdgcn_s_setprio(0);
            }
            // R9: full pin at phase end — nothing (incl. DS/MFMA) crosses,
            // so no cross-phase liveness growth (R8's spill cause).
            __builtin_amdgcn_sched_barrier(0);
        }
    }

    // Epilogue: C/D layout col=lane&15 (px), row=quad*4+reg (o)
    const int Pbase = px_blk * 256 + wp;
#pragma unroll
    for (int i = 0; i < 4; ++i) {
#pragma unroll
        for (int jj = 0; jj < 8; ++jj) {
            const int P = Pbase + jj * 16 + l15;
            const int hw = P & 4095;
            float* op = out + (size_t)n * 1048576 + hw;
#pragma unroll
            for (int r = 0; r < 4; ++r) {
                const int o = o_blk * 128 + wo + i * 16 + quad * 4 + r;
                op[(size_t)o * 4096] = acc[i][jj][r];
            }
        }
    }
}

extern "C" void kernel_launch(void* const* d_in, const int* in_sizes, int n_in,
                              void* d_out, int out_size, void* d_ws, size_t ws_size,
                              hipStream_t stream) {
    const float* x = (const float*)d_in[0];
    const float* w = (const float*)d_in[1];
    float* out = (float*)d_out;
    __hip_bfloat16* xt = (__hip_bfloat16*)d_ws;
    __hip_bfloat16* wm = (__hip_bfloat16*)((char*)d_ws + XT_BYTES);

    prep_w_kernel<<<1152, 256, 0, stream>>>(w, wm);
    transpose_x_kernel<<<2048, 256, 0, stream>>>(x, xt);
    gemm_kernel<<<dim3(512, 2), 256, 0, stream>>>(xt, wm, out);
}